// Round 8
// baseline (110.678 us; speedup 1.0000x reference)
//
#include <hip/hip_runtime.h>

#define GRID  2048
#define BLOCK 256

typedef float f4 __attribute__((ext_vector_type(4)));
typedef int   i4 __attribute__((ext_vector_type(4)));

// ws layout: [0..GRID)        pos partials (f32)
//            [GRID..2*GRID)   neg partials (f32)
//            [2*GRID..3*GRID) pos counts  (u32)

__device__ __forceinline__ void proc_elem(float pv, int tv,
                                          float& posd, float& allsp, float& possp,
                                          float& cntf)
{
    float a    = fabsf(pv);
    float em   = __expf(-a);            // exp(-|p|) in (0,1]
    float lc   = __logf(1.0f + em);     // log1p(exp(-|p|)), stable
    float sp   = fmaxf(pv, 0.0f) + lc;  // softplus(p)
    float diff = sp - pv;               // softplus(-p)
    float t    = (float)tv;             // tv in {0,1}
    posd  = fmaf(t, diff, posd);        // sum over pos of softplus(-p)
    allsp += sp;                        // sum over all of softplus(p)
    possp = fmaf(t, sp, possp);         // sum over pos of softplus(p)
    cntf  += t;
}

__device__ __forceinline__ void proc4(const f4 p, const i4 t,
                                      float& posd, float& allsp, float& possp,
                                      float& cntf)
{
    proc_elem(p[0], t[0], posd, allsp, possp, cntf);
    proc_elem(p[1], t[1], posd, allsp, possp, cntf);
    proc_elem(p[2], t[2], posd, allsp, possp, cntf);
    proc_elem(p[3], t[3], posd, allsp, possp, cntf);
}

// one "group" = 2 x (float4,int4) = 8 elements/lane, 4 vmem loads
#define LOADG(X0, X1, Y0, Y1) \
    do { X0 = pred4[i]; X1 = pred4[i + T]; Y0 = ty4[i]; Y1 = ty4[i + T]; i += 2 * T; } while (0)
#define PROCG(X0, X1, Y0, Y1) \
    do { proc4(X0, Y0, posd, allsp, possp, cntf); proc4(X1, Y1, posd, allsp, possp, cntf); } while (0)

__global__ __launch_bounds__(BLOCK) void formicro_reduce(
    const f4* __restrict__ pred4,
    const i4* __restrict__ ty4,
    int n4,
    const float* __restrict__ pred_s,
    const int*   __restrict__ ty_s,
    int n,
    float* __restrict__ ws)
{
    const int T   = gridDim.x * blockDim.x;
    const int gid = blockIdx.x * blockDim.x + threadIdx.x;

    float posd = 0.f, allsp = 0.f, possp = 0.f, cntf = 0.f;

    // depth-2 software pipeline, modulus-3 unrolled (no buffer copies, all
    // register indices static). While processing one group, TWO groups
    // (8 loads) are in flight.
    const int iters = n4 / (2 * T);   // groups per thread; 16 at 8192^2
    int i = gid;
    if (iters >= 2) {
        f4 Xa0, Xa1, Xb0, Xb1, Xc0, Xc1;
        i4 Ya0, Ya1, Yb0, Yb1, Yc0, Yc1;
        LOADG(Xa0, Xa1, Ya0, Ya1);            // group g
        LOADG(Xb0, Xb1, Yb0, Yb1);            // group g+1
        int g = 0;
        for (; g + 4 < iters; g += 3) {
            LOADG(Xc0, Xc1, Yc0, Yc1);        // issue g+2
            PROCG(Xa0, Xa1, Ya0, Ya1);        // consume g
            LOADG(Xa0, Xa1, Ya0, Ya1);        // issue g+3
            PROCG(Xb0, Xb1, Yb0, Yb1);        // consume g+1
            LOADG(Xb0, Xb1, Yb0, Yb1);        // issue g+4
            PROCG(Xc0, Xc1, Yc0, Yc1);        // consume g+2
        }
        const int rem = iters - g;            // 2, 3, or 4 (uniform)
        if (rem == 2) {
            PROCG(Xa0, Xa1, Ya0, Ya1);
            PROCG(Xb0, Xb1, Yb0, Yb1);
        } else if (rem == 3) {
            LOADG(Xc0, Xc1, Yc0, Yc1);
            PROCG(Xa0, Xa1, Ya0, Ya1);
            PROCG(Xb0, Xb1, Yb0, Yb1);
            PROCG(Xc0, Xc1, Yc0, Yc1);
        } else { // rem == 4
            LOADG(Xc0, Xc1, Yc0, Yc1);
            PROCG(Xa0, Xa1, Ya0, Ya1);
            LOADG(Xa0, Xa1, Ya0, Ya1);
            PROCG(Xb0, Xb1, Yb0, Yb1);
            PROCG(Xc0, Xc1, Yc0, Yc1);
            PROCG(Xa0, Xa1, Ya0, Ya1);
        }
    }
    // leftover float4s (dead at 8192^2 but kept for generality)
    for (; i < n4; i += T) {
        f4 p = pred4[i];
        i4 t = ty4[i];
        proc4(p, t, posd, allsp, possp, cntf);
    }
    // scalar tail (n % 4)
    for (int k = (n4 << 2) + gid; k < n; k += T) {
        proc_elem(pred_s[k], ty_s[k], posd, allsp, possp, cntf);
    }

    float negs = allsp - possp;   // sum over neg of softplus(p)

    // wave-64 reduction
    #pragma unroll
    for (int off = 32; off > 0; off >>= 1) {
        posd += __shfl_down(posd, off);
        negs += __shfl_down(negs, off);
        cntf += __shfl_down(cntf, off);
    }

    __shared__ float spos[BLOCK / 64];
    __shared__ float sneg[BLOCK / 64];
    __shared__ float scnt[BLOCK / 64];
    const int wid  = threadIdx.x >> 6;
    const int lane = threadIdx.x & 63;
    if (lane == 0) { spos[wid] = posd; sneg[wid] = negs; scnt[wid] = cntf; }
    __syncthreads();

    if (threadIdx.x == 0) {
        float P = 0.f, Ng = 0.f, C = 0.f;
        #pragma unroll
        for (int w = 0; w < BLOCK / 64; ++w) { P += spos[w]; Ng += sneg[w]; C += scnt[w]; }
        ws[blockIdx.x]        = P;
        ws[GRID + blockIdx.x] = Ng;
        ((unsigned*)ws)[2 * GRID + blockIdx.x] = (unsigned)C;  // <= 32768, exact
    }
}

__global__ __launch_bounds__(BLOCK) void formicro_finalize(
    const float* __restrict__ ws, float* __restrict__ out, float total)
{
    float posd = 0.f, negs = 0.f;
    unsigned cnt = 0;
    for (int i = threadIdx.x; i < GRID; i += BLOCK) {
        posd += ws[i];
        negs += ws[GRID + i];
        cnt  += ((const unsigned*)ws)[2 * GRID + i];
    }
    #pragma unroll
    for (int off = 32; off > 0; off >>= 1) {
        posd += __shfl_down(posd, off);
        negs += __shfl_down(negs, off);
        cnt  += __shfl_down(cnt, off);
    }
    __shared__ float    spos[BLOCK / 64];
    __shared__ float    sneg[BLOCK / 64];
    __shared__ unsigned scnt[BLOCK / 64];
    const int wid  = threadIdx.x >> 6;
    const int lane = threadIdx.x & 63;
    if (lane == 0) { spos[wid] = posd; sneg[wid] = negs; scnt[wid] = cnt; }
    __syncthreads();
    if (threadIdx.x == 0) {
        float P = 0.f, Ng = 0.f;
        unsigned C = 0;
        #pragma unroll
        for (int w = 0; w < BLOCK / 64; ++w) { P += spos[w]; Ng += sneg[w]; C += scnt[w]; }
        float npos = (float)C;
        float nneg = total - npos;
        out[0] = P / npos + Ng / nneg;
    }
}

extern "C" void kernel_launch(void* const* d_in, const int* in_sizes, int n_in,
                              void* d_out, int out_size, void* d_ws, size_t ws_size,
                              hipStream_t stream)
{
    const float* pred = (const float*)d_in[0];
    const int*   ty   = (const int*)d_in[1];
    float*       out  = (float*)d_out;
    float*       ws   = (float*)d_ws;

    int n  = in_sizes[0];   // 8192*8192 = 67108864
    int n4 = n >> 2;

    formicro_reduce<<<GRID, BLOCK, 0, stream>>>(
        (const f4*)pred, (const i4*)ty, n4, pred, ty, n, ws);

    formicro_finalize<<<1, BLOCK, 0, stream>>>(ws, out, (float)n);
}

// Round 9
// 108.472 us; speedup vs baseline: 1.0203x; 1.0203x over previous
//
#include <hip/hip_runtime.h>

#define GRID  2048
#define BLOCK 256

typedef float f4 __attribute__((ext_vector_type(4)));
typedef int   i4 __attribute__((ext_vector_type(4)));

// ws layout: [0..GRID)        pos partials (f32)
//            [GRID..2*GRID)   neg partials (f32)
//            [2*GRID..3*GRID) pos counts  (u32)

__device__ __forceinline__ void proc_elem(float pv, int tv,
                                          float& posd, float& allsp, float& possp,
                                          float& cntf)
{
    float a    = fabsf(pv);
    float em   = __expf(-a);            // exp(-|p|) in (0,1]
    float lc   = __logf(1.0f + em);     // log1p(exp(-|p|)), stable
    float sp   = fmaxf(pv, 0.0f) + lc;  // softplus(p)
    float diff = sp - pv;               // softplus(-p)
    float t    = (float)tv;             // tv in {0,1}
    posd  = fmaf(t, diff, posd);        // sum over pos of softplus(-p)
    allsp += sp;                        // sum over all of softplus(p)
    possp = fmaf(t, sp, possp);         // sum over pos of softplus(p)
    cntf  += t;
}

__device__ __forceinline__ void proc4(const f4 p, const i4 t,
                                      float& posd, float& allsp, float& possp,
                                      float& cntf)
{
    proc_elem(p[0], t[0], posd, allsp, possp, cntf);
    proc_elem(p[1], t[1], posd, allsp, possp, cntf);
    proc_elem(p[2], t[2], posd, allsp, possp, cntf);
    proc_elem(p[3], t[3], posd, allsp, possp, cntf);
}

__global__ __launch_bounds__(BLOCK) void formicro_reduce(
    const f4* __restrict__ pred4,
    const i4* __restrict__ ty4,
    int n4,
    const float* __restrict__ pred_s,
    const int*   __restrict__ ty_s,
    int n,
    float* __restrict__ ws)
{
    const int T   = gridDim.x * blockDim.x;
    const int gid = blockIdx.x * blockDim.x + threadIdx.x;

    float posd = 0.f, allsp = 0.f, possp = 0.f, cntf = 0.f;

    // depth-1 software pipeline (rotate-by-one): prefetch one group
    // (2 x float4 + 2 x int4 = 4 loads) ahead so loads are in flight
    // during every compute phase. Measured optimum (R7: 103.9 us);
    // depth-2 regressed via VGPR/occupancy (R8), UNROLL-8 null (R3).
    const int iters = n4 / (2 * T);   // 16 at 8192^2
    int i = gid;
    if (iters > 0) {
        f4 P0 = pred4[i], P1 = pred4[i + T];
        i4 L0 = ty4[i],   L1 = ty4[i + T];
        i += 2 * T;
        for (int g = 0; g < iters - 1; ++g) {
            f4 Q0 = pred4[i];
            f4 Q1 = pred4[i + T];
            i4 M0 = ty4[i];
            i4 M1 = ty4[i + T];
            proc4(P0, L0, posd, allsp, possp, cntf);
            proc4(P1, L1, posd, allsp, possp, cntf);
            P0 = Q0; P1 = Q1; L0 = M0; L1 = M1;
            i += 2 * T;
        }
        proc4(P0, L0, posd, allsp, possp, cntf);
        proc4(P1, L1, posd, allsp, possp, cntf);
    }
    // leftover float4s (dead at 8192^2 but kept for generality)
    for (; i < n4; i += T) {
        f4 p = pred4[i];
        i4 t = ty4[i];
        proc4(p, t, posd, allsp, possp, cntf);
    }
    // scalar tail (n % 4)
    for (int k = (n4 << 2) + gid; k < n; k += T) {
        proc_elem(pred_s[k], ty_s[k], posd, allsp, possp, cntf);
    }

    float negs = allsp - possp;   // sum over neg of softplus(p)

    // wave-64 reduction
    #pragma unroll
    for (int off = 32; off > 0; off >>= 1) {
        posd += __shfl_down(posd, off);
        negs += __shfl_down(negs, off);
        cntf += __shfl_down(cntf, off);
    }

    __shared__ float spos[BLOCK / 64];
    __shared__ float sneg[BLOCK / 64];
    __shared__ float scnt[BLOCK / 64];
    const int wid  = threadIdx.x >> 6;
    const int lane = threadIdx.x & 63;
    if (lane == 0) { spos[wid] = posd; sneg[wid] = negs; scnt[wid] = cntf; }
    __syncthreads();

    if (threadIdx.x == 0) {
        float P = 0.f, Ng = 0.f, C = 0.f;
        #pragma unroll
        for (int w = 0; w < BLOCK / 64; ++w) { P += spos[w]; Ng += sneg[w]; C += scnt[w]; }
        ws[blockIdx.x]        = P;
        ws[GRID + blockIdx.x] = Ng;
        ((unsigned*)ws)[2 * GRID + blockIdx.x] = (unsigned)C;  // <= 32768, exact
    }
}

__global__ __launch_bounds__(BLOCK) void formicro_finalize(
    const float* __restrict__ ws, float* __restrict__ out, float total)
{
    float posd = 0.f, negs = 0.f;
    unsigned cnt = 0;
    for (int i = threadIdx.x; i < GRID; i += BLOCK) {
        posd += ws[i];
        negs += ws[GRID + i];
        cnt  += ((const unsigned*)ws)[2 * GRID + i];
    }
    #pragma unroll
    for (int off = 32; off > 0; off >>= 1) {
        posd += __shfl_down(posd, off);
        negs += __shfl_down(negs, off);
        cnt  += __shfl_down(cnt, off);
    }
    __shared__ float    spos[BLOCK / 64];
    __shared__ float    sneg[BLOCK / 64];
    __shared__ unsigned scnt[BLOCK / 64];
    const int wid  = threadIdx.x >> 6;
    const int lane = threadIdx.x & 63;
    if (lane == 0) { spos[wid] = posd; sneg[wid] = negs; scnt[wid] = cnt; }
    __syncthreads();
    if (threadIdx.x == 0) {
        float P = 0.f, Ng = 0.f;
        unsigned C = 0;
        #pragma unroll
        for (int w = 0; w < BLOCK / 64; ++w) { P += spos[w]; Ng += sneg[w]; C += scnt[w]; }
        float npos = (float)C;
        float nneg = total - npos;
        out[0] = P / npos + Ng / nneg;
    }
}

extern "C" void kernel_launch(void* const* d_in, const int* in_sizes, int n_in,
                              void* d_out, int out_size, void* d_ws, size_t ws_size,
                              hipStream_t stream)
{
    const float* pred = (const float*)d_in[0];
    const int*   ty   = (const int*)d_in[1];
    float*       out  = (float*)d_out;
    float*       ws   = (float*)d_ws;

    int n  = in_sizes[0];   // 8192*8192 = 67108864
    int n4 = n >> 2;

    formicro_reduce<<<GRID, BLOCK, 0, stream>>>(
        (const f4*)pred, (const i4*)ty, n4, pred, ty, n, ws);

    formicro_finalize<<<1, BLOCK, 0, stream>>>(ws, out, (float)n);
}